// Round 1
// baseline (3400.392 us; speedup 1.0000x reference)
//
#include <hip/hip_runtime.h>

// ---------------------------------------------------------------------------
// SyndromeTransformer fused kernel (fp32 baseline)
// B=16384, S=8, F=16, D=256, H=4, K=16, E=4, EH=128
// One block = NB(2) batch elements = 16 token rows. 256 threads.
// All intermediates in LDS; weights stream from L2 (total ~2.9MB, L2-resident).
// Conv on the 4x4 grid reduced to block-sparse GEMM over 5 taps + precomputed
// pad-cell contribution (padc, computed per-launch into d_ws).
// ---------------------------------------------------------------------------

#define DEVI __device__ __forceinline__

namespace {

constexpr int STA = 260;   // stride of 16x256 buffers (pad 4 floats: bank shift + float4 aligned)
constexpr int STH = 516;   // stride of 16x512 hid buffer
constexpr int STC = 68;    // stride of 16x64 ctx buffer

constexpr int OFF_A   = 0;
constexpr int OFF_B   = OFF_A + 16 * STA;     // 4160
constexpr int OFF_H   = OFF_B + 16 * STA;     // 8320  (also holds QKV 16x196 early)
constexpr int OFF_CTX = OFF_H + 16 * STH;     // 16576
constexpr int OFF_G   = OFF_CTX + 16 * STC;   // 17664
constexpr int OFF_X   = OFF_G + 64;           // 17728
constexpr int SMEM_TOT = OFF_X + 256;         // 17984 floats = 71936 B -> 2 blocks/CU

DEVI float dot4f(const float4& h, float a, float b, float c, float d) {
  return h.x * a + h.y * b + h.z * c + h.w * d;
}

// LayerNorm 16 rows x 256 cols in-place. Wave w handles rows 4w..4w+3.
DEVI void ln_inplace(float* buf, const float* __restrict__ sc,
                     const float* __restrict__ of, int tid) {
  const int w = tid >> 6, lane = tid & 63;
  #pragma unroll
  for (int rr = 0; rr < 4; ++rr) {
    float* row = buf + (w * 4 + rr) * STA;
    float v0 = row[lane], v1 = row[lane + 64], v2 = row[lane + 128], v3 = row[lane + 192];
    float s1 = v0 + v1 + v2 + v3;
    float s2 = v0 * v0 + v1 * v1 + v2 * v2 + v3 * v3;
    #pragma unroll
    for (int m = 1; m < 64; m <<= 1) {
      s1 += __shfl_xor(s1, m, 64);
      s2 += __shfl_xor(s2, m, 64);
    }
    float mean = s1 * (1.0f / 256.0f);
    float var  = s2 * (1.0f / 256.0f) - mean * mean;
    float rstd = rsqrtf(var + 1e-5f);
    row[lane]       = sc[lane]       * (v0 - mean) * rstd + of[lane];
    row[lane + 64]  = sc[lane + 64]  * (v1 - mean) * rstd + of[lane + 64];
    row[lane + 128] = sc[lane + 128] * (v2 - mean) * rstd + of[lane + 128];
    row[lane + 192] = sc[lane + 192] * (v3 - mean) * rstd + of[lane + 192];
  }
}

// LayerNorm 16 rows, write to global out (rows are contiguous tokens).
DEVI void ln_to_global(const float* buf, const float* __restrict__ sc,
                       const float* __restrict__ of, int tid,
                       float* __restrict__ outp) {
  const int w = tid >> 6, lane = tid & 63;
  #pragma unroll
  for (int rr = 0; rr < 4; ++rr) {
    const int r = w * 4 + rr;
    const float* row = buf + r * STA;
    float v0 = row[lane], v1 = row[lane + 64], v2 = row[lane + 128], v3 = row[lane + 192];
    float s1 = v0 + v1 + v2 + v3;
    float s2 = v0 * v0 + v1 * v1 + v2 * v2 + v3 * v3;
    #pragma unroll
    for (int m = 1; m < 64; m <<= 1) {
      s1 += __shfl_xor(s1, m, 64);
      s2 += __shfl_xor(s2, m, 64);
    }
    float mean = s1 * (1.0f / 256.0f);
    float var  = s2 * (1.0f / 256.0f) - mean * mean;
    float rstd = rsqrtf(var + 1e-5f);
    float* orow = outp + (size_t)r * 256;
    orow[lane]       = sc[lane]       * (v0 - mean) * rstd + of[lane];
    orow[lane + 64]  = sc[lane + 64]  * (v1 - mean) * rstd + of[lane + 64];
    orow[lane + 128] = sc[lane + 128] * (v2 - mean) * rstd + of[lane + 128];
    orow[lane + 192] = sc[lane + 192] * (v3 - mean) * rstd + of[lane + 192];
  }
}

}  // namespace

// ---------------------------------------------------------------------------
// padc[s][d] = conv_b[d] + sum over edge-adjacent in-bounds pad cells of
//              pad_vec @ conv_w[tap].  Batch-independent; 8 blocks x 256 thr.
// taps linear index = kr*3+kc.
// ---------------------------------------------------------------------------
__global__ void padc_kernel(const float* __restrict__ pad_vec,
                            const float* __restrict__ conv_w,
                            const float* __restrict__ conv_b,
                            float* __restrict__ padc) {
  const int s = blockIdx.x;
  const int d = threadIdx.x;
  // even-neighbor taps per gathered cell (derived from the checkerboard
  // scatter ROWS/COLS): -1 = unused
  const int NP[8]     = {3, 2, 3, 4, 4, 3, 2, 3};
  const int PT[8][4]  = {{7, 3, 5, -1}, {7, 3, -1, -1}, {1, 7, 5, -1}, {1, 7, 3, 5},
                         {1, 7, 3, 5},  {1, 7, 3, -1},  {1, 5, -1, -1}, {1, 3, 5, -1}};
  float acc = conv_b[d];
  for (int t = 0; t < NP[s]; ++t) {
    const float* W = conv_w + PT[s][t] * 65536;
    for (int k = 0; k < 256; ++k) acc += pad_vec[k] * W[k * 256 + d];
  }
  padc[s * 256 + d] = acc;
}

// ---------------------------------------------------------------------------
// Main fused kernel.
// ---------------------------------------------------------------------------
__global__ __launch_bounds__(256, 2) void fused_main(
    const float* __restrict__ x,
    const float* __restrict__ w_embed, const float* __restrict__ b_embed,
    const float* __restrict__ wq, const float* __restrict__ bq,
    const float* __restrict__ wk, const float* __restrict__ bk,
    const float* __restrict__ wvw, const float* __restrict__ bv,
    const float* __restrict__ wo, const float* __restrict__ bo,
    const float* __restrict__ ln1_s, const float* __restrict__ ln1_b,
    const float* __restrict__ wg, const float* __restrict__ bg,
    const float* __restrict__ w1, const float* __restrict__ b1,
    const float* __restrict__ w2, const float* __restrict__ b2,
    const float* __restrict__ ln2_s, const float* __restrict__ ln2_b,
    const float* __restrict__ convw, const float* __restrict__ padc,
    const float* __restrict__ ln3_s, const float* __restrict__ ln3_b,
    float* __restrict__ out) {
  __shared__ __align__(16) float smem[SMEM_TOT];
  float* sA   = smem + OFF_A;    // 16 x 256 (stride 260)
  float* sB   = smem + OFF_B;    // 16 x 256
  float* sH   = smem + OFF_H;    // 16 x 512 (stride 516); early: qkv 16x192 (stride 196)
  float* sCTX = smem + OFF_CTX;  // 16 x 64  (stride 68)
  float* sG   = smem + OFF_G;    // 16 x 4 gate
  float* sX   = smem + OFF_X;    // 16 x 16 input

  const int tid = threadIdx.x;
  const int b0  = blockIdx.x * 2;  // first batch element of this block

  // ---- load x (2 batches x 8 tokens x 16 feats = 256 floats) ----
  sX[tid] = x[(size_t)b0 * 128 + tid];
  __syncthreads();

  // ---- step 1: h = x @ w_embed + b_embed -> sA ----
  {
    const int c = tid;
    float acc[16];
    const float bias = b_embed[c];
    #pragma unroll
    for (int r = 0; r < 16; ++r) acc[r] = bias;
    for (int k = 0; k < 16; ++k) {
      const float wv = w_embed[k * 256 + c];
      #pragma unroll
      for (int r = 0; r < 16; ++r) acc[r] += sX[r * 16 + k] * wv;
    }
    #pragma unroll
    for (int r = 0; r < 16; ++r) sA[r * STA + c] = acc[r];
  }
  __syncthreads();

  // ---- step 2: qkv = h @ [wq|wk|wv] + bias (q scaled 1/sqrt(16)) -> sH[r][196] ----
  if (tid < 192) {
    const int m = tid >> 6, col = tid & 63;
    const float* W = (m == 0) ? wq : (m == 1) ? wk : wvw;
    const float bias = (m == 0) ? bq[col] : (m == 1) ? bk[col] : bv[col];
    float acc[16];
    #pragma unroll
    for (int r = 0; r < 16; ++r) acc[r] = bias;
    for (int k4 = 0; k4 < 64; ++k4) {
      const float w0 = W[(4 * k4 + 0) * 64 + col];
      const float w1v = W[(4 * k4 + 1) * 64 + col];
      const float w2v = W[(4 * k4 + 2) * 64 + col];
      const float w3 = W[(4 * k4 + 3) * 64 + col];
      #pragma unroll
      for (int r = 0; r < 16; ++r) {
        const float4 h4 = *reinterpret_cast<const float4*>(&sA[r * STA + 4 * k4]);
        acc[r] += dot4f(h4, w0, w1v, w2v, w3);
      }
    }
    const float scale = (m == 0) ? 0.25f : 1.0f;
    #pragma unroll
    for (int r = 0; r < 16; ++r) sH[r * 196 + tid] = acc[r] * scale;
  }
  __syncthreads();

  // ---- step 3: attention (per (b_local, head, query_row); 64 threads) ----
  if (tid < 64) {
    const int bl = tid >> 5, hh = (tid >> 3) & 3, qi = tid & 7;
    const int rb = bl * 8;
    float qv[16];
    #pragma unroll
    for (int kk = 0; kk < 16; ++kk) qv[kk] = sH[(rb + qi) * 196 + hh * 16 + kk];
    float lg[8];
    #pragma unroll
    for (int j = 0; j < 8; ++j) {
      float d = 0.f;
      #pragma unroll
      for (int kk = 0; kk < 16; ++kk) d += qv[kk] * sH[(rb + j) * 196 + 64 + hh * 16 + kk];
      lg[j] = d;
    }
    float mx = lg[0];
    #pragma unroll
    for (int j = 1; j < 8; ++j) mx = fmaxf(mx, lg[j]);
    float ssum = 0.f;
    #pragma unroll
    for (int j = 0; j < 8; ++j) { lg[j] = __expf(lg[j] - mx); ssum += lg[j]; }
    const float inv = 1.0f / ssum;
    #pragma unroll
    for (int kk = 0; kk < 16; ++kk) {
      float cv = 0.f;
      #pragma unroll
      for (int j = 0; j < 8; ++j) cv += lg[j] * sH[(rb + j) * 196 + 128 + hh * 16 + kk];
      sCTX[(rb + qi) * STC + hh * 16 + kk] = cv * inv;
    }
  }
  __syncthreads();

  // ---- step 4: attn_out = ctx @ wo + bo; sB = h + attn_out ----
  {
    const int c = tid;
    float acc[16];
    const float bias = bo[c];
    #pragma unroll
    for (int r = 0; r < 16; ++r) acc[r] = bias;
    for (int k4 = 0; k4 < 16; ++k4) {
      const float w0 = wo[(4 * k4 + 0) * 256 + c];
      const float w1v = wo[(4 * k4 + 1) * 256 + c];
      const float w2v = wo[(4 * k4 + 2) * 256 + c];
      const float w3 = wo[(4 * k4 + 3) * 256 + c];
      #pragma unroll
      for (int r = 0; r < 16; ++r) {
        const float4 c4 = *reinterpret_cast<const float4*>(&sCTX[r * STC + 4 * k4]);
        acc[r] += dot4f(c4, w0, w1v, w2v, w3);
      }
    }
    #pragma unroll
    for (int r = 0; r < 16; ++r) sB[r * STA + c] = sA[r * STA + c] + acc[r];
  }
  __syncthreads();
  ln_inplace(sB, ln1_s, ln1_b, tid);  // sB = h1
  __syncthreads();

  // ---- step 6: gate = softmax(h1 @ wg + bg) -> sG ----
  if (tid < 64) {
    const int r = tid >> 2, e = tid & 3;
    float d = bg[e];
    for (int k4 = 0; k4 < 64; ++k4) {
      const float4 h4 = *reinterpret_cast<const float4*>(&sB[r * STA + 4 * k4]);
      d += h4.x * wg[(4 * k4 + 0) * 4 + e] + h4.y * wg[(4 * k4 + 1) * 4 + e] +
           h4.z * wg[(4 * k4 + 2) * 4 + e] + h4.w * wg[(4 * k4 + 3) * 4 + e];
    }
    float mx = d;
    mx = fmaxf(mx, __shfl_xor(mx, 1, 64));
    mx = fmaxf(mx, __shfl_xor(mx, 2, 64));
    float p = __expf(d - mx);
    float ss = p;
    ss += __shfl_xor(ss, 1, 64);
    ss += __shfl_xor(ss, 2, 64);
    sG[r * 4 + e] = p / ss;
  }
  __syncthreads();

  // ---- step 7: hid = gate_e * relu(h1 @ w1 + b1) -> sH (16 x 512) ----
  {
    const int cg0 = tid, cg1 = tid + 256;
    const int e0 = cg0 >> 7, c0 = cg0 & 127;
    const int e1 = cg1 >> 7, c1 = cg1 & 127;
    const float* W0 = w1 + e0 * 32768;
    const float* W1 = w1 + e1 * 32768;
    float acc0[16], acc1[16];
    const float bv0 = b1[e0 * 128 + c0], bv1 = b1[e1 * 128 + c1];
    #pragma unroll
    for (int r = 0; r < 16; ++r) { acc0[r] = bv0; acc1[r] = bv1; }
    for (int k4 = 0; k4 < 64; ++k4) {
      const float a0 = W0[(4 * k4 + 0) * 128 + c0];
      const float a1 = W0[(4 * k4 + 1) * 128 + c0];
      const float a2 = W0[(4 * k4 + 2) * 128 + c0];
      const float a3 = W0[(4 * k4 + 3) * 128 + c0];
      const float u0 = W1[(4 * k4 + 0) * 128 + c1];
      const float u1 = W1[(4 * k4 + 1) * 128 + c1];
      const float u2 = W1[(4 * k4 + 2) * 128 + c1];
      const float u3 = W1[(4 * k4 + 3) * 128 + c1];
      #pragma unroll
      for (int r = 0; r < 16; ++r) {
        const float4 h4 = *reinterpret_cast<const float4*>(&sB[r * STA + 4 * k4]);
        acc0[r] += dot4f(h4, a0, a1, a2, a3);
        acc1[r] += dot4f(h4, u0, u1, u2, u3);
      }
    }
    #pragma unroll
    for (int r = 0; r < 16; ++r) {
      sH[r * STH + cg0] = sG[r * 4 + e0] * fmaxf(acc0[r], 0.f);
      sH[r * STH + cg1] = sG[r * 4 + e1] * fmaxf(acc1[r], 0.f);
    }
  }
  __syncthreads();

  // ---- step 8: moe = hid @ w2cat (+ gate-weighted b2); sA = h1 + moe ----
  {
    const int c = tid;
    float acc[16];
    #pragma unroll
    for (int r = 0; r < 16; ++r) {
      acc[r] = sG[r * 4 + 0] * b2[c] + sG[r * 4 + 1] * b2[256 + c] +
               sG[r * 4 + 2] * b2[512 + c] + sG[r * 4 + 3] * b2[768 + c];
    }
    for (int k4 = 0; k4 < 128; ++k4) {
      const float w0 = w2[(4 * k4 + 0) * 256 + c];
      const float w1v = w2[(4 * k4 + 1) * 256 + c];
      const float w2v = w2[(4 * k4 + 2) * 256 + c];
      const float w3 = w2[(4 * k4 + 3) * 256 + c];
      #pragma unroll
      for (int r = 0; r < 16; ++r) {
        const float4 h4 = *reinterpret_cast<const float4*>(&sH[r * STH + 4 * k4]);
        acc[r] += dot4f(h4, w0, w1v, w2v, w3);
      }
    }
    #pragma unroll
    for (int r = 0; r < 16; ++r) sA[r * STA + c] = sB[r * STA + c] + acc[r];
  }
  __syncthreads();
  ln_inplace(sA, ln2_s, ln2_b, tid);  // sA = h2
  __syncthreads();

  // ---- step 9: conv as block-sparse GEMM over 5 taps; sB = h2 + conv + padc ----
  {
    const int c = tid;
    float acc[16];
    #pragma unroll
    for (int bl = 0; bl < 2; ++bl)
      #pragma unroll
      for (int s = 0; s < 8; ++s) acc[bl * 8 + s] = padc[s * 256 + c];

    // taps: t0=(0,0) t1=(0,2) t2=(1,1) t3=(2,0) t4=(2,2); linear*65536 floats
    const int TAPOFF[5] = {0 * 65536, 2 * 65536, 4 * 65536, 6 * 65536, 8 * 65536};
    for (int k4 = 0; k4 < 64; ++k4) {
      float wt[5][4];
      #pragma unroll
      for (int t = 0; t < 5; ++t) {
        #pragma unroll
        for (int j = 0; j < 4; ++j) wt[t][j] = convw[TAPOFF[t] + (4 * k4 + j) * 256 + c];
      }
      #pragma unroll
      for (int bl = 0; bl < 2; ++bl) {
        const float* base = &sA[bl * 8 * STA + 4 * k4];
        float4 h4;
#define CACC(dst, t) acc[bl * 8 + (dst)] += dot4f(h4, wt[t][0], wt[t][1], wt[t][2], wt[t][3])
        h4 = *reinterpret_cast<const float4*>(base + 0 * STA);  // src 0
        CACC(0, 2); CACC(2, 1); CACC(3, 0);
        h4 = *reinterpret_cast<const float4*>(base + 1 * STA);  // src 1
        CACC(1, 2); CACC(3, 1);
        h4 = *reinterpret_cast<const float4*>(base + 2 * STA);  // src 2
        CACC(0, 3); CACC(2, 2); CACC(4, 0);
        h4 = *reinterpret_cast<const float4*>(base + 3 * STA);  // src 3
        CACC(0, 4); CACC(1, 3); CACC(3, 2); CACC(4, 1); CACC(5, 0);
        h4 = *reinterpret_cast<const float4*>(base + 4 * STA);  // src 4
        CACC(2, 4); CACC(3, 3); CACC(4, 2); CACC(6, 1); CACC(7, 0);
        h4 = *reinterpret_cast<const float4*>(base + 5 * STA);  // src 5
        CACC(3, 4); CACC(5, 2); CACC(7, 1);
        h4 = *reinterpret_cast<const float4*>(base + 6 * STA);  // src 6
        CACC(4, 3); CACC(6, 2);
        h4 = *reinterpret_cast<const float4*>(base + 7 * STA);  // src 7
        CACC(4, 4); CACC(5, 3); CACC(7, 2);
#undef CACC
      }
    }
    #pragma unroll
    for (int r = 0; r < 16; ++r) sB[r * STA + c] = sA[r * STA + c] + acc[r];
  }
  __syncthreads();

  // ---- step 10: out = LN3(h2 + conv) ----
  ln_to_global(sB, ln3_s, ln3_b, tid, out + (size_t)b0 * 8 * 256);
}

extern "C" void kernel_launch(void* const* d_in, const int* in_sizes, int n_in,
                              void* d_out, int out_size, void* d_ws, size_t ws_size,
                              hipStream_t stream) {
  const float* x       = (const float*)d_in[0];
  const float* w_embed = (const float*)d_in[1];
  const float* b_embed = (const float*)d_in[2];
  const float* wq      = (const float*)d_in[3];
  const float* bq      = (const float*)d_in[4];
  const float* wk      = (const float*)d_in[5];
  const float* bk      = (const float*)d_in[6];
  const float* wv      = (const float*)d_in[7];
  const float* bv      = (const float*)d_in[8];
  const float* wo      = (const float*)d_in[9];
  const float* bo      = (const float*)d_in[10];
  const float* ln1_s   = (const float*)d_in[11];
  const float* ln1_b   = (const float*)d_in[12];
  const float* wg      = (const float*)d_in[13];
  const float* bg      = (const float*)d_in[14];
  const float* w1      = (const float*)d_in[15];
  const float* b1      = (const float*)d_in[16];
  const float* w2      = (const float*)d_in[17];
  const float* b2      = (const float*)d_in[18];
  const float* ln2_s   = (const float*)d_in[19];
  const float* ln2_b   = (const float*)d_in[20];
  const float* pad_vec = (const float*)d_in[21];
  const float* conv_w  = (const float*)d_in[22];
  const float* conv_b  = (const float*)d_in[23];
  const float* ln3_s   = (const float*)d_in[24];
  const float* ln3_b   = (const float*)d_in[25];

  float* padc = (float*)d_ws;  // 8 x 256 floats

  padc_kernel<<<8, 256, 0, stream>>>(pad_vec, conv_w, conv_b, padc);
  fused_main<<<16384 / 2, 256, 0, stream>>>(
      x, w_embed, b_embed, wq, bq, wk, bk, wv, bv, wo, bo,
      ln1_s, ln1_b, wg, bg, w1, b1, w2, b2, ln2_s, ln2_b,
      conv_w, padc, ln3_s, ln3_b, (float*)d_out);
}

// Round 6
// 606.323 us; speedup vs baseline: 5.6082x; 5.6082x over previous
//
#include <hip/hip_runtime.h>

// ---------------------------------------------------------------------------
// SyndromeTransformer fused, bf16-MFMA version.
// B=16384, S=8, F=16, D=256, H=4, K=16, E=4, EH=128
// Block = 4 batch elems = 32 token rows, 512 threads (8 waves), grid 4096.
// GEMMs (QKV, WO, MoE1, MoE2, conv-taps) via v_mfma_f32_16x16x32_bf16.
// Weights pre-converted per launch into fragment-major bf16 in d_ws.
// LN / softmax / attention / gate / residuals in fp32.
// Conv = 5-tap block-sparse GEMM (checkerboard) + precomputed pad term padc.
// ---------------------------------------------------------------------------

typedef short bf16x8 __attribute__((ext_vector_type(8)));
typedef float f32x4 __attribute__((ext_vector_type(4)));

union FragU { uint4 u; bf16x8 h; };

#define MFMA(a, b, c) __builtin_amdgcn_mfma_f32_16x16x32_bf16((a), (b), (c), 0, 0, 0)

__device__ __forceinline__ unsigned short f2b(float f) {
  union { float f; unsigned int u; } x; x.f = f;
  unsigned int r = x.u + 0x7FFFu + ((x.u >> 16) & 1u);
  return (unsigned short)(r >> 16);
}

// fragment-region offsets (units of 1KB frags = 64 lanes x 16B)
constexpr int FR_QKV  = 0;     // K=256,N=192: 12 nt x 8 ks
constexpr int FR_WO   = 96;    // K=64, N=256: 16 nt x 2 ks
constexpr int FR_W1   = 128;   // K=256,N=512: 32 nt x 8 ks
constexpr int FR_W2   = 384;   // K=512,N=256: 16 nt x 16 ks
constexpr int FR_CONV = 640;   // 5 taps x (16 nt x 8 ks)
constexpr int FR_TOT  = 1280;
constexpr size_t PADC_BYTE_OFF = (size_t)FR_TOT * 1024;  // 1,310,720

// LDS layout (bytes)
constexpr int OFF_HF = 0;        // f32 [32][260] residual stream h / h1 / h2
constexpr int OFF_ST = 33280;    // f32 [32][260] LN staging; alias qkv [32][200]
constexpr int OFF_HB = 66560;    // u16 [32][264] bf16 copy of h (MFMA A)
constexpr int OFF_MB = 83456;    // u16 [32][520] bf16 moe hidden (MFMA A)
constexpr int OFF_CB = 116736;   // u16 [32][72]  bf16 ctx (MFMA A)
constexpr int OFF_G  = 121344;   // f32 [128] gate
constexpr int OFF_X  = 121856;   // f32 [512] input x
constexpr int SMEM_BYTES = 123904;

__device__ __forceinline__ bf16x8 ldsFrag(const unsigned short* base, int elemOff) {
  FragU x; x.u = *(const uint4*)(base + elemOff); return x.h;
}
__device__ __forceinline__ bf16x8 ldw(const uint4* wsf, int frag, int l) {
  FragU x; x.u = wsf[(size_t)frag * 64 + l]; return x.h;
}

// ---------------------------------------------------------------------------
// Weight prep: fp32 -> bf16 fragment-major. 320 blocks x 256 thr = 1280 frags.
// frag(nt,ks,lane,e) = B[ks*32 + (lane>>4)*8 + e][nt*16 + (lane&15)]
// ---------------------------------------------------------------------------
__global__ void prep_weights(const float* __restrict__ wq, const float* __restrict__ wk,
                             const float* __restrict__ wv, const float* __restrict__ wo,
                             const float* __restrict__ w1, const float* __restrict__ w2,
                             const float* __restrict__ conv_w,
                             unsigned short* __restrict__ wsb) {
  const int flat = blockIdx.x * 256 + threadIdx.x;
  const int f = flat >> 6, l = flat & 63;
  const int nl = l & 15, rq = l >> 4;
  float v[8];
  if (f < FR_WO) {  // qkv
    const int g = f, nt = g >> 3, ks = g & 7, n = nt * 16 + nl;
    #pragma unroll
    for (int e = 0; e < 8; ++e) {
      const int k = ks * 32 + rq * 8 + e;
      v[e] = (n < 64) ? wq[k * 64 + n] : (n < 128) ? wk[k * 64 + n - 64] : wv[k * 64 + n - 128];
    }
  } else if (f < FR_W1) {  // wo
    const int g = f - FR_WO, nt = g >> 1, ks = g & 1, n = nt * 16 + nl;
    #pragma unroll
    for (int e = 0; e < 8; ++e) {
      const int k = ks * 32 + rq * 8 + e;
      v[e] = wo[k * 256 + n];
    }
  } else if (f < FR_W2) {  // w1: B[k][e*128+h] = w1[e][k][h]
    const int g = f - FR_W1, nt = g >> 3, ks = g & 7, n = nt * 16 + nl;
    const int ee = n >> 7, hh = n & 127;
    #pragma unroll
    for (int e = 0; e < 8; ++e) {
      const int k = ks * 32 + rq * 8 + e;
      v[e] = w1[(ee * 256 + k) * 128 + hh];
    }
  } else if (f < FR_CONV) {  // w2: B[e*128+h][n] = w2[e][h][n]
    const int g = f - FR_W2, nt = g >> 4, ks = g & 15, n = nt * 16 + nl;
    #pragma unroll
    for (int e = 0; e < 8; ++e) {
      const int k = ks * 32 + rq * 8 + e;
      const int ei = k >> 7, hh = k & 127;
      v[e] = w2[(ei * 128 + hh) * 256 + n];
    }
  } else {  // conv taps {(0,0),(0,2),(1,1),(2,0),(2,2)} -> linear 2*tap
    const int g = f - FR_CONV, tap = g >> 7, r = g & 127, nt = r >> 3, ks = r & 7;
    const int n = nt * 16 + nl;
    #pragma unroll
    for (int e = 0; e < 8; ++e) {
      const int k = ks * 32 + rq * 8 + e;
      v[e] = conv_w[(size_t)(2 * tap) * 65536 + k * 256 + n];
    }
  }
  FragU fr;
  fr.u.x = (unsigned int)f2b(v[0]) | ((unsigned int)f2b(v[1]) << 16);
  fr.u.y = (unsigned int)f2b(v[2]) | ((unsigned int)f2b(v[3]) << 16);
  fr.u.z = (unsigned int)f2b(v[4]) | ((unsigned int)f2b(v[5]) << 16);
  fr.u.w = (unsigned int)f2b(v[6]) | ((unsigned int)f2b(v[7]) << 16);
  *(uint4*)(wsb + (size_t)f * 512 + l * 8) = fr.u;
}

// ---------------------------------------------------------------------------
// padc[s][d] = conv_b[d] + pad-cell contributions (verified in round 1)
// ---------------------------------------------------------------------------
__global__ void padc_kernel(const float* __restrict__ pad_vec,
                            const float* __restrict__ conv_w,
                            const float* __restrict__ conv_b,
                            float* __restrict__ padc) {
  const int s = blockIdx.x;
  const int d = threadIdx.x;
  const int NP[8]    = {3, 2, 3, 4, 4, 3, 2, 3};
  const int PT[8][4] = {{7, 3, 5, -1}, {7, 3, -1, -1}, {1, 7, 5, -1}, {1, 7, 3, 5},
                        {1, 7, 3, 5},  {1, 7, 3, -1},  {1, 5, -1, -1}, {1, 3, 5, -1}};
  float acc = conv_b[d];
  for (int t = 0; t < NP[s]; ++t) {
    const float* W = conv_w + PT[s][t] * 65536;
    for (int k = 0; k < 256; ++k) acc += pad_vec[k] * W[k * 256 + d];
  }
  padc[s * 256 + d] = acc;
}

// ---------------------------------------------------------------------------
// LN helpers (32 rows, 8 waves x 4 rows)
// ---------------------------------------------------------------------------
__device__ __forceinline__ void ln_dual(const float* src, float* dstF, unsigned short* dstB,
                                        const float* __restrict__ sc, const float* __restrict__ of,
                                        int wid, int l) {
  #pragma unroll
  for (int rr = 0; rr < 4; ++rr) {
    const int r = wid * 4 + rr;
    const float* row = src + r * 260;
    float v0 = row[l], v1 = row[l + 64], v2 = row[l + 128], v3 = row[l + 192];
    float s1 = v0 + v1 + v2 + v3;
    float s2 = v0 * v0 + v1 * v1 + v2 * v2 + v3 * v3;
    #pragma unroll
    for (int m = 1; m < 64; m <<= 1) { s1 += __shfl_xor(s1, m, 64); s2 += __shfl_xor(s2, m, 64); }
    const float mean = s1 * (1.0f / 256.0f);
    const float var  = s2 * (1.0f / 256.0f) - mean * mean;
    const float rstd = rsqrtf(var + 1e-5f);
    const float o0 = sc[l] * (v0 - mean) * rstd + of[l];
    const float o1 = sc[l + 64] * (v1 - mean) * rstd + of[l + 64];
    const float o2 = sc[l + 128] * (v2 - mean) * rstd + of[l + 128];
    const float o3 = sc[l + 192] * (v3 - mean) * rstd + of[l + 192];
    dstF[r * 260 + l] = o0; dstF[r * 260 + l + 64] = o1;
    dstF[r * 260 + l + 128] = o2; dstF[r * 260 + l + 192] = o3;
    dstB[r * 264 + l] = f2b(o0); dstB[r * 264 + l + 64] = f2b(o1);
    dstB[r * 264 + l + 128] = f2b(o2); dstB[r * 264 + l + 192] = f2b(o3);
  }
}

__device__ __forceinline__ void ln_out(const float* src, const float* __restrict__ sc,
                                       const float* __restrict__ of, int wid, int l,
                                       float* __restrict__ outp) {
  #pragma unroll
  for (int rr = 0; rr < 4; ++rr) {
    const int r = wid * 4 + rr;
    const float* row = src + r * 260;
    float v0 = row[l], v1 = row[l + 64], v2 = row[l + 128], v3 = row[l + 192];
    float s1 = v0 + v1 + v2 + v3;
    float s2 = v0 * v0 + v1 * v1 + v2 * v2 + v3 * v3;
    #pragma unroll
    for (int m = 1; m < 64; m <<= 1) { s1 += __shfl_xor(s1, m, 64); s2 += __shfl_xor(s2, m, 64); }
    const float mean = s1 * (1.0f / 256.0f);
    const float var  = s2 * (1.0f / 256.0f) - mean * mean;
    const float rstd = rsqrtf(var + 1e-5f);
    float* orow = outp + (size_t)r * 256;
    orow[l]       = sc[l] * (v0 - mean) * rstd + of[l];
    orow[l + 64]  = sc[l + 64] * (v1 - mean) * rstd + of[l + 64];
    orow[l + 128] = sc[l + 128] * (v2 - mean) * rstd + of[l + 128];
    orow[l + 192] = sc[l + 192] * (v3 - mean) * rstd + of[l + 192];
  }
}

// ---------------------------------------------------------------------------
// Main fused kernel
// ---------------------------------------------------------------------------
__global__ __launch_bounds__(512, 2) void fused_main(
    const float* __restrict__ x,
    const float* __restrict__ w_embed, const float* __restrict__ b_embed,
    const float* __restrict__ bq, const float* __restrict__ bk, const float* __restrict__ bv,
    const float* __restrict__ bo,
    const float* __restrict__ ln1_s, const float* __restrict__ ln1_b,
    const float* __restrict__ wg, const float* __restrict__ bg,
    const float* __restrict__ b1, const float* __restrict__ b2,
    const float* __restrict__ ln2_s, const float* __restrict__ ln2_b,
    const float* __restrict__ ln3_s, const float* __restrict__ ln3_b,
    const uint4* __restrict__ wsf, const float* __restrict__ padc,
    float* __restrict__ out) {
  __shared__ __align__(16) unsigned char smem[SMEM_BYTES];
  float* sHf = (float*)(smem + OFF_HF);            // [32][260]
  float* sSt = (float*)(smem + OFF_ST);            // [32][260]
  float* sQ  = sSt;                                 // alias [32][200] qkv
  unsigned short* sHb = (unsigned short*)(smem + OFF_HB);  // [32][264]
  unsigned short* sMb = (unsigned short*)(smem + OFF_MB);  // [32][520]
  unsigned short* sCb = (unsigned short*)(smem + OFF_CB);  // [32][72]
  float* sG = (float*)(smem + OFF_G);
  float* sX = (float*)(smem + OFF_X);

  const int tid = threadIdx.x;
  const int wid = tid >> 6, l = tid & 63, rq = l >> 4, nl = l & 15;

  // ---- P0: load x (4 batches x 8 tok x 16 feat = 512) ----
  sX[tid] = x[(size_t)blockIdx.x * 512 + tid];
  __syncthreads();

  // ---- P1: embed (fp32): h = x @ w_embed + b_embed -> sHf, sHb ----
  {
    const int c = tid & 255, r0 = (tid >> 8) * 16;
    float acc[16];
    const float bb = b_embed[c];
    #pragma unroll
    for (int r = 0; r < 16; ++r) acc[r] = bb;
    #pragma unroll
    for (int k = 0; k < 16; ++k) {
      const float w = w_embed[k * 256 + c];
      #pragma unroll
      for (int r = 0; r < 16; ++r) acc[r] += sX[(r0 + r) * 16 + k] * w;
    }
    #pragma unroll
    for (int r = 0; r < 16; ++r) {
      sHf[(r0 + r) * 260 + c] = acc[r];
      sHb[(r0 + r) * 264 + c] = f2b(acc[r]);
    }
  }
  __syncthreads();

  // ---- P2: QKV MFMA (12 nt; q scaled 0.25) -> sQ fp32 [32][200] ----
  for (int pass = 0; pass < 2; ++pass) {
    const int nt = (pass == 0) ? wid : (wid < 4 ? 8 + wid : -1);
    if (nt < 0) break;
    f32x4 a0 = {0.f, 0.f, 0.f, 0.f}, a1 = {0.f, 0.f, 0.f, 0.f};
    #pragma unroll
    for (int ks = 0; ks < 8; ++ks) {
      const bf16x8 A0 = ldsFrag(sHb, nl * 264 + ks * 32 + rq * 8);
      const bf16x8 A1 = ldsFrag(sHb, (16 + nl) * 264 + ks * 32 + rq * 8);
      const bf16x8 Bf = ldw(wsf, FR_QKV + nt * 8 + ks, l);
      a0 = MFMA(A0, Bf, a0);
      a1 = MFMA(A1, Bf, a1);
    }
    const int n = nt * 16 + nl;
    const float bias = (n < 64) ? bq[n] : (n < 128) ? bk[n - 64] : bv[n - 128];
    const float scl = (n < 64) ? 0.25f : 1.0f;
    #pragma unroll
    for (int i = 0; i < 4; ++i) {
      sQ[(rq * 4 + i) * 200 + n] = (a0[i] + bias) * scl;
      sQ[(16 + rq * 4 + i) * 200 + n] = (a1[i] + bias) * scl;
    }
  }
  __syncthreads();

  // ---- P3: attention (fp32; 128 threads = 4 bl x 4 head x 8 q) ----
  if (tid < 128) {
    const int bl = tid >> 5, hh = (tid >> 3) & 3, qi = tid & 7, rb = bl * 8;
    const float* qrow = &sQ[(rb + qi) * 200 + hh * 16];
    float qv[16];
    #pragma unroll
    for (int kk = 0; kk < 16; kk += 4) {
      const float4 q4 = *(const float4*)&qrow[kk];
      qv[kk] = q4.x; qv[kk + 1] = q4.y; qv[kk + 2] = q4.z; qv[kk + 3] = q4.w;
    }
    float lg[8];
    #pragma unroll
    for (int j = 0; j < 8; ++j) {
      const float* krow = &sQ[(rb + j) * 200 + 64 + hh * 16];
      float d = 0.f;
      #pragma unroll
      for (int kk = 0; kk < 16; kk += 4) {
        const float4 k4 = *(const float4*)&krow[kk];
        d += qv[kk] * k4.x + qv[kk + 1] * k4.y + qv[kk + 2] * k4.z + qv[kk + 3] * k4.w;
      }
      lg[j] = d;
    }
    float mx = lg[0];
    #pragma unroll
    for (int j = 1; j < 8; ++j) mx = fmaxf(mx, lg[j]);
    float ssum = 0.f;
    #pragma unroll
    for (int j = 0; j < 8; ++j) { lg[j] = __expf(lg[j] - mx); ssum += lg[j]; }
    const float inv = 1.0f / ssum;
    #pragma unroll
    for (int kk = 0; kk < 16; kk += 4) {
      float c0 = 0.f, c1 = 0.f, c2 = 0.f, c3 = 0.f;
      #pragma unroll
      for (int j = 0; j < 8; ++j) {
        const float4 v4 = *(const float4*)&sQ[(rb + j) * 200 + 128 + hh * 16 + kk];
        c0 += lg[j] * v4.x; c1 += lg[j] * v4.y; c2 += lg[j] * v4.z; c3 += lg[j] * v4.w;
      }
      const int cb = (rb + qi) * 72 + hh * 16 + kk;
      sCb[cb] = f2b(c0 * inv); sCb[cb + 1] = f2b(c1 * inv);
      sCb[cb + 2] = f2b(c2 * inv); sCb[cb + 3] = f2b(c3 * inv);
    }
  }
  __syncthreads();

  // ---- P4: WO MFMA + residual -> sSt; LN1 -> sHf(h1), sHb ----
  {
    #pragma unroll
    for (int j = 0; j < 2; ++j) {
      const int nt = wid * 2 + j;
      f32x4 a0 = {0.f, 0.f, 0.f, 0.f}, a1 = {0.f, 0.f, 0.f, 0.f};
      #pragma unroll
      for (int ks = 0; ks < 2; ++ks) {
        const bf16x8 A0 = ldsFrag(sCb, nl * 72 + ks * 32 + rq * 8);
        const bf16x8 A1 = ldsFrag(sCb, (16 + nl) * 72 + ks * 32 + rq * 8);
        const bf16x8 Bf = ldw(wsf, FR_WO + nt * 2 + ks, l);
        a0 = MFMA(A0, Bf, a0);
        a1 = MFMA(A1, Bf, a1);
      }
      const int n = nt * 16 + nl;
      const float bb = bo[n];
      #pragma unroll
      for (int i = 0; i < 4; ++i) {
        const int g0 = rq * 4 + i, g1 = 16 + rq * 4 + i;
        sSt[g0 * 260 + n] = a0[i] + bb + sHf[g0 * 260 + n];
        sSt[g1 * 260 + n] = a1[i] + bb + sHf[g1 * 260 + n];
      }
    }
  }
  __syncthreads();
  ln_dual(sSt, sHf, sHb, ln1_s, ln1_b, wid, l);
  __syncthreads();

  // ---- P5: gate = softmax(h1 @ wg + bg) (fp32, 128 threads) ----
  if (tid < 128) {
    const int r = tid >> 2, e = tid & 3;
    float d = bg[e];
    for (int k4 = 0; k4 < 64; ++k4) {
      const float4 h4 = *(const float4*)&sHf[r * 260 + 4 * k4];
      d += h4.x * wg[(4 * k4 + 0) * 4 + e] + h4.y * wg[(4 * k4 + 1) * 4 + e] +
           h4.z * wg[(4 * k4 + 2) * 4 + e] + h4.w * wg[(4 * k4 + 3) * 4 + e];
    }
    float mx = fmaxf(d, __shfl_xor(d, 1, 64));
    mx = fmaxf(mx, __shfl_xor(mx, 2, 64));
    const float p = __expf(d - mx);
    float ss = p + __shfl_xor(p, 1, 64);
    ss += __shfl_xor(ss, 2, 64);
    sG[r * 4 + e] = p / ss;
  }
  __syncthreads();

  // ---- P6: MoE1 MFMA: hid = gate * relu(h1@w1 + b1) -> sMb bf16 [32][520] ----
  {
    f32x4 acc[4][2];
    #pragma unroll
    for (int j = 0; j < 4; ++j)
      #pragma unroll
      for (int mt = 0; mt < 2; ++mt) acc[j][mt] = {0.f, 0.f, 0.f, 0.f};
    #pragma unroll
    for (int ks = 0; ks < 8; ++ks) {
      const bf16x8 A0 = ldsFrag(sHb, nl * 264 + ks * 32 + rq * 8);
      const bf16x8 A1 = ldsFrag(sHb, (16 + nl) * 264 + ks * 32 + rq * 8);
      #pragma unroll
      for (int j = 0; j < 4; ++j) {
        const bf16x8 Bf = ldw(wsf, FR_W1 + (wid * 4 + j) * 8 + ks, l);
        acc[j][0] = MFMA(A0, Bf, acc[j][0]);
        acc[j][1] = MFMA(A1, Bf, acc[j][1]);
      }
    }
    #pragma unroll
    for (int j = 0; j < 4; ++j) {
      const int n = (wid * 4 + j) * 16 + nl, e = n >> 7;
      const float b1v = b1[e * 128 + (n & 127)];
      #pragma unroll
      for (int mt = 0; mt < 2; ++mt)
        #pragma unroll
        for (int i = 0; i < 4; ++i) {
          const int gr = mt * 16 + rq * 4 + i;
          const float g = sG[gr * 4 + e];
          sMb[gr * 520 + n] = f2b(g * fmaxf(acc[j][mt][i] + b1v, 0.f));
        }
    }
  }
  __syncthreads();

  // ---- P7: MoE2 MFMA + gate-weighted b2 + residual -> sSt; LN2 -> sHf(h2), sHb ----
  {
    f32x4 acc[2][2];
    #pragma unroll
    for (int j = 0; j < 2; ++j)
      #pragma unroll
      for (int mt = 0; mt < 2; ++mt) acc[j][mt] = {0.f, 0.f, 0.f, 0.f};
    #pragma unroll
    for (int ks = 0; ks < 16; ++ks) {
      const bf16x8 A0 = ldsFrag(sMb, nl * 520 + ks * 32 + rq * 8);
      const bf16x8 A1 = ldsFrag(sMb, (16 + nl) * 520 + ks * 32 + rq * 8);
      #pragma unroll
      for (int j = 0; j < 2; ++j) {
        const bf16x8 Bf = ldw(wsf, FR_W2 + (wid * 2 + j) * 16 + ks, l);
        acc[j][0] = MFMA(A0, Bf, acc[j][0]);
        acc[j][1] = MFMA(A1, Bf, acc[j][1]);
      }
    }
    #pragma unroll
    for (int j = 0; j < 2; ++j) {
      const int n = (wid * 2 + j) * 16 + nl;
      const float bA = b2[n], bB = b2[256 + n], bC = b2[512 + n], bD = b2[768 + n];
      #pragma unroll
      for (int mt = 0; mt < 2; ++mt)
        #pragma unroll
        for (int i = 0; i < 4; ++i) {
          const int gr = mt * 16 + rq * 4 + i;
          const float val = acc[j][mt][i] + sG[gr * 4 + 0] * bA + sG[gr * 4 + 1] * bB +
                            sG[gr * 4 + 2] * bC + sG[gr * 4 + 3] * bD + sHf[gr * 260 + n];
          sSt[gr * 260 + n] = val;
        }
    }
  }
  __syncthreads();
  ln_dual(sSt, sHf, sHb, ln2_s, ln2_b, wid, l);
  __syncthreads();

  // ---- P8: conv = 5-tap block-sparse MFMA + padc + residual -> sSt; LN3 -> out ----
  {
    // per-tap dst->src token map, nibble-encoded (0xF = no source)
    const unsigned int ENC[5] = {0x4F320FFFu, 0x54F310FFu, 0x76543210u, 0xFF764F32u, 0xFFF754F3u};
    f32x4 acc[2][2];
    #pragma unroll
    for (int j = 0; j < 2; ++j) {
      const int n = (wid * 2 + j) * 16 + nl;
      #pragma unroll
      for (int mt = 0; mt < 2; ++mt)
        #pragma unroll
        for (int i = 0; i < 4; ++i)
          acc[j][mt][i] = padc[((rq * 4 + i) & 7) * 256 + n];
    }
    #pragma unroll
    for (int tap = 0; tap < 5; ++tap) {
      const int nib = (int)((ENC[tap] >> ((nl & 7) * 4)) & 0xF);
      const bool valid = (nib != 15);
      const int srow = (nl & 8) + (nib & 7);  // source row within 16-row subtile
      #pragma unroll
      for (int ks = 0; ks < 8; ++ks) {
        FragU fa0, fa1;
        fa0.u = *(const uint4*)(sHb + srow * 264 + ks * 32 + rq * 8);
        fa1.u = *(const uint4*)(sHb + (16 + srow) * 264 + ks * 32 + rq * 8);
        if (!valid) { fa0.u = make_uint4(0, 0, 0, 0); fa1.u = make_uint4(0, 0, 0, 0); }
        #pragma unroll
        for (int j = 0; j < 2; ++j) {
          const bf16x8 Bf = ldw(wsf, FR_CONV + tap * 128 + (wid * 2 + j) * 8 + ks, l);
          acc[j][0] = MFMA(fa0.h, Bf, acc[j][0]);
          acc[j][1] = MFMA(fa1.h, Bf, acc[j][1]);
        }
      }
    }
    #pragma unroll
    for (int j = 0; j < 2; ++j) {
      const int n = (wid * 2 + j) * 16 + nl;
      #pragma unroll
      for (int mt = 0; mt < 2; ++mt)
        #pragma unroll
        for (int i = 0; i < 4; ++i) {
          const int gr = mt * 16 + rq * 4 + i;
          sSt[gr * 260 + n] = acc[j][mt][i] + sHf[gr * 260 + n];
        }
    }
  }
  __syncthreads();
  ln_out(sSt, ln3_s, ln3_b, wid, l, out + (size_t)blockIdx.x * 32 * 256);
}

// ---------------------------------------------------------------------------
extern "C" void kernel_launch(void* const* d_in, const int* in_sizes, int n_in,
                              void* d_out, int out_size, void* d_ws, size_t ws_size,
                              hipStream_t stream) {
  const float* x       = (const float*)d_in[0];
  const float* w_embed = (const float*)d_in[1];
  const float* b_embed = (const float*)d_in[2];
  const float* wq      = (const float*)d_in[3];
  const float* bq      = (const float*)d_in[4];
  const float* wk      = (const float*)d_in[5];
  const float* bk      = (const float*)d_in[6];
  const float* wv      = (const float*)d_in[7];
  const float* bv      = (const float*)d_in[8];
  const float* wo      = (const float*)d_in[9];
  const float* bo      = (const float*)d_in[10];
  const float* ln1_s   = (const float*)d_in[11];
  const float* ln1_b   = (const float*)d_in[12];
  const float* wg      = (const float*)d_in[13];
  const float* bg      = (const float*)d_in[14];
  const float* w1      = (const float*)d_in[15];
  const float* b1      = (const float*)d_in[16];
  const float* w2      = (const float*)d_in[17];
  const float* b2      = (const float*)d_in[18];
  const float* ln2_s   = (const float*)d_in[19];
  const float* ln2_b   = (const float*)d_in[20];
  const float* pad_vec = (const float*)d_in[21];
  const float* conv_w  = (const float*)d_in[22];
  const float* conv_b  = (const float*)d_in[23];
  const float* ln3_s   = (const float*)d_in[24];
  const float* ln3_b   = (const float*)d_in[25];

  unsigned short* wsb = (unsigned short*)d_ws;
  float* padc = (float*)((char*)d_ws + PADC_BYTE_OFF);

  prep_weights<<<320, 256, 0, stream>>>(wq, wk, wv, wo, w1, w2, conv_w, wsb);
  padc_kernel<<<8, 256, 0, stream>>>(pad_vec, conv_w, conv_b, padc);
  fused_main<<<4096, 512, 0, stream>>>(
      x, w_embed, b_embed, bq, bk, bv, bo, ln1_s, ln1_b, wg, bg, b1, b2,
      ln2_s, ln2_b, ln3_s, ln3_b, (const uint4*)d_ws, padc, (float*)d_out);
}

// Round 11
// 535.484 us; speedup vs baseline: 6.3501x; 1.1323x over previous
//
#include <hip/hip_runtime.h>

// ---------------------------------------------------------------------------
// SyndromeTransformer fused, bf16-MFMA, register-resident residual stream.
// B=16384, S=8, F=16, D=256, H=4, K=16, E=4, EH=128
// Block = 4 batch elems = 32 rows, 512 threads (8 waves), grid 4096.
// Per-thread ownership: rows gr = mt*16+rq*4+i, cols n = (wid*2+j)*16+nl
//   -> residual h/h1/h2 kept in 16 VGPRs (hR[2][2][4]); no f32 LDS buffers.
// LayerNorm: 16-lane shuffle reduce + sLN[32][16] cross-wave combine.
// LDS 59.4 KB -> 2 blocks/CU (vs 124 KB -> 1 block in round 6).
// ---------------------------------------------------------------------------

typedef short bf16x8 __attribute__((ext_vector_type(8)));
typedef float f32x4 __attribute__((ext_vector_type(4)));

union FragU { uint4 u; bf16x8 h; };

#define MFMA(a, b, c) __builtin_amdgcn_mfma_f32_16x16x32_bf16((a), (b), (c), 0, 0, 0)

__device__ __forceinline__ unsigned short f2b(float f) {
  union { float f; unsigned int u; } x; x.f = f;
  unsigned int r = x.u + 0x7FFFu + ((x.u >> 16) & 1u);
  return (unsigned short)(r >> 16);
}
__device__ __forceinline__ float b2f(unsigned int us) {
  union { unsigned int u; float f; } x; x.u = us << 16; return x.f;
}

// fragment-region offsets (units of 1KB frags = 64 lanes x 16B)
constexpr int FR_QKV  = 0;     // K=256,N=192: 12 nt x 8 ks
constexpr int FR_WO   = 96;    // K=64, N=256: 16 nt x 2 ks
constexpr int FR_W1   = 128;   // K=256,N=512: 32 nt x 8 ks
constexpr int FR_W2   = 384;   // K=512,N=256: 16 nt x 16 ks
constexpr int FR_CONV = 640;   // 5 taps x (16 nt x 8 ks)
constexpr int FR_TOT  = 1280;
constexpr size_t PADC_BYTE_OFF = (size_t)FR_TOT * 1024;

// LDS layout (bytes)
constexpr int OFF_HB = 0;        // u16 [32][264] bf16 h/h1/h2 (MFMA A)      16896
constexpr int OFF_MQ = 16896;    // region 33280: sQ f32 [32][200] (P2-P3),
                                 //               hid u16 [32][520] (P6-P7)
constexpr int OFF_CB = 50176;    // u16 [32][72] bf16 ctx                     4608
constexpr int OFF_X  = 54784;    // f32 [512] input x                         2048
constexpr int OFF_G  = 56832;    // f32 [128] gate                             512
constexpr int OFF_LN = 57344;    // f32 [32][16] LN partials (s1,s2 x 8 wid)  2048
constexpr int SMEM_BYTES = 59392;

__device__ __forceinline__ bf16x8 ldsFrag(const unsigned short* base, int elemOff) {
  FragU x; x.u = *(const uint4*)(base + elemOff); return x.h;
}
__device__ __forceinline__ bf16x8 ldw(const uint4* wsf, int frag, int l) {
  FragU x; x.u = wsf[(size_t)frag * 64 + l]; return x.h;
}

// LN partial reduce: per-thread 8 rows x 2 cols -> sLN[row][wid*2 +{0,1}]
__device__ __forceinline__ void ln_part(const float nv[2][2][4], float* sLN,
                                        int wid, int rq, int nl) {
  float p1[2][4], p2[2][4];
  #pragma unroll
  for (int mt = 0; mt < 2; ++mt)
    #pragma unroll
    for (int i = 0; i < 4; ++i) {
      const float a = nv[0][mt][i], b = nv[1][mt][i];
      p1[mt][i] = a + b;
      p2[mt][i] = a * a + b * b;
    }
  #pragma unroll
  for (int m = 1; m < 16; m <<= 1) {
    #pragma unroll
    for (int mt = 0; mt < 2; ++mt)
      #pragma unroll
      for (int i = 0; i < 4; ++i) {
        p1[mt][i] += __shfl_xor(p1[mt][i], m, 64);
        p2[mt][i] += __shfl_xor(p2[mt][i], m, 64);
      }
  }
  if (nl == 0) {
    #pragma unroll
    for (int mt = 0; mt < 2; ++mt)
      #pragma unroll
      for (int i = 0; i < 4; ++i) {
        const int row = mt * 16 + rq * 4 + i;
        sLN[row * 16 + wid * 2]     = p1[mt][i];
        sLN[row * 16 + wid * 2 + 1] = p2[mt][i];
      }
  }
}

__device__ __forceinline__ void ln_stats(const float* sLN, int rq,
                                         float mean[2][4], float rstd[2][4]) {
  #pragma unroll
  for (int mt = 0; mt < 2; ++mt)
    #pragma unroll
    for (int i = 0; i < 4; ++i) {
      const int row = mt * 16 + rq * 4 + i;
      float s1 = 0.f, s2 = 0.f;
      #pragma unroll
      for (int w = 0; w < 8; ++w) {
        const float2 p = *(const float2*)&sLN[row * 16 + 2 * w];
        s1 += p.x; s2 += p.y;
      }
      const float m = s1 * (1.0f / 256.0f);
      const float v = s2 * (1.0f / 256.0f) - m * m;
      mean[mt][i] = m;
      rstd[mt][i] = rsqrtf(v + 1e-5f);
    }
}

// ---------------------------------------------------------------------------
// Weight prep (unchanged - verified round 6).
// ---------------------------------------------------------------------------
__global__ void prep_weights(const float* __restrict__ wq, const float* __restrict__ wk,
                             const float* __restrict__ wv, const float* __restrict__ wo,
                             const float* __restrict__ w1, const float* __restrict__ w2,
                             const float* __restrict__ conv_w,
                             unsigned short* __restrict__ wsb) {
  const int flat = blockIdx.x * 256 + threadIdx.x;
  const int f = flat >> 6, l = flat & 63;
  const int nl = l & 15, rq = l >> 4;
  float v[8];
  if (f < FR_WO) {
    const int g = f, nt = g >> 3, ks = g & 7, n = nt * 16 + nl;
    #pragma unroll
    for (int e = 0; e < 8; ++e) {
      const int k = ks * 32 + rq * 8 + e;
      v[e] = (n < 64) ? wq[k * 64 + n] : (n < 128) ? wk[k * 64 + n - 64] : wv[k * 64 + n - 128];
    }
  } else if (f < FR_W1) {
    const int g = f - FR_WO, nt = g >> 1, ks = g & 1, n = nt * 16 + nl;
    #pragma unroll
    for (int e = 0; e < 8; ++e) {
      const int k = ks * 32 + rq * 8 + e;
      v[e] = wo[k * 256 + n];
    }
  } else if (f < FR_W2) {
    const int g = f - FR_W1, nt = g >> 3, ks = g & 7, n = nt * 16 + nl;
    const int ee = n >> 7, hh = n & 127;
    #pragma unroll
    for (int e = 0; e < 8; ++e) {
      const int k = ks * 32 + rq * 8 + e;
      v[e] = w1[(ee * 256 + k) * 128 + hh];
    }
  } else if (f < FR_CONV) {
    const int g = f - FR_W2, nt = g >> 4, ks = g & 15, n = nt * 16 + nl;
    #pragma unroll
    for (int e = 0; e < 8; ++e) {
      const int k = ks * 32 + rq * 8 + e;
      const int ei = k >> 7, hh = k & 127;
      v[e] = w2[(ei * 128 + hh) * 256 + n];
    }
  } else {
    const int g = f - FR_CONV, tap = g >> 7, r = g & 127, nt = r >> 3, ks = r & 7;
    const int n = nt * 16 + nl;
    #pragma unroll
    for (int e = 0; e < 8; ++e) {
      const int k = ks * 32 + rq * 8 + e;
      v[e] = conv_w[(size_t)(2 * tap) * 65536 + k * 256 + n];
    }
  }
  FragU fr;
  fr.u.x = (unsigned int)f2b(v[0]) | ((unsigned int)f2b(v[1]) << 16);
  fr.u.y = (unsigned int)f2b(v[2]) | ((unsigned int)f2b(v[3]) << 16);
  fr.u.z = (unsigned int)f2b(v[4]) | ((unsigned int)f2b(v[5]) << 16);
  fr.u.w = (unsigned int)f2b(v[6]) | ((unsigned int)f2b(v[7]) << 16);
  *(uint4*)(wsb + (size_t)f * 512 + l * 8) = fr.u;
}

// ---------------------------------------------------------------------------
// padc: parallelized 4x over k-chunks.
// ---------------------------------------------------------------------------
__global__ void padc_kernel(const float* __restrict__ pad_vec,
                            const float* __restrict__ conv_w,
                            const float* __restrict__ conv_b,
                            float* __restrict__ padc) {
  __shared__ float part[4][256];
  const int s = blockIdx.x;
  const int d = threadIdx.x & 255;
  const int q = threadIdx.x >> 8;
  const int NP[8]    = {3, 2, 3, 4, 4, 3, 2, 3};
  const int PT[8][4] = {{7, 3, 5, -1}, {7, 3, -1, -1}, {1, 7, 5, -1}, {1, 7, 3, 5},
                        {1, 7, 3, 5},  {1, 7, 3, -1},  {1, 5, -1, -1}, {1, 3, 5, -1}};
  float acc = 0.f;
  for (int t = 0; t < NP[s]; ++t) {
    const float* W = conv_w + PT[s][t] * 65536 + q * 64 * 256;
    const float* pv = pad_vec + q * 64;
    for (int k = 0; k < 64; ++k) acc += pv[k] * W[k * 256 + d];
  }
  part[q][d] = acc;
  __syncthreads();
  if (q == 0) padc[s * 256 + d] = conv_b[d] + part[0][d] + part[1][d] + part[2][d] + part[3][d];
}

// ---------------------------------------------------------------------------
// Main fused kernel
// ---------------------------------------------------------------------------
__global__ __launch_bounds__(512, 4) void fused_main(
    const float* __restrict__ x,
    const float* __restrict__ w_embed, const float* __restrict__ b_embed,
    const float* __restrict__ bq, const float* __restrict__ bk, const float* __restrict__ bv,
    const float* __restrict__ bo,
    const float* __restrict__ ln1_s, const float* __restrict__ ln1_b,
    const float* __restrict__ wg, const float* __restrict__ bg,
    const float* __restrict__ b1, const float* __restrict__ b2,
    const float* __restrict__ ln2_s, const float* __restrict__ ln2_b,
    const float* __restrict__ ln3_s, const float* __restrict__ ln3_b,
    const uint4* __restrict__ wsf, const float* __restrict__ padc,
    float* __restrict__ out) {
  __shared__ __align__(16) unsigned char smem[SMEM_BYTES];
  unsigned short* sHb = (unsigned short*)(smem + OFF_HB);
  float* sQ           = (float*)(smem + OFF_MQ);
  unsigned short* sMb = (unsigned short*)(smem + OFF_MQ);
  unsigned short* sCb = (unsigned short*)(smem + OFF_CB);
  float* sX  = (float*)(smem + OFF_X);
  float* sG  = (float*)(smem + OFF_G);
  float* sLN = (float*)(smem + OFF_LN);

  const int tid = threadIdx.x;
  const int wid = tid >> 6, l = tid & 63, rq = l >> 4, nl = l & 15;
  const int n0 = wid * 32 + nl, n1 = n0 + 16;  // cols j=0,1

  float hR[2][2][4];  // residual stream, [j][mt][i]
  float nv[2][2][4];  // pre-LN staging

  // ---- P0: load x ----
  sX[tid] = x[(size_t)blockIdx.x * 512 + tid];
  __syncthreads();

  // ---- P1: embed into register ownership + sHb ----
  {
    float wc0[16], wc1[16];
    #pragma unroll
    for (int k = 0; k < 16; ++k) {
      wc0[k] = w_embed[k * 256 + n0];
      wc1[k] = w_embed[k * 256 + n1];
    }
    const float bb0 = b_embed[n0], bb1 = b_embed[n1];
    #pragma unroll
    for (int mt = 0; mt < 2; ++mt)
      #pragma unroll
      for (int i = 0; i < 4; ++i) {
        const int gr = mt * 16 + rq * 4 + i;
        float a0 = bb0, a1 = bb1;
        #pragma unroll
        for (int kk = 0; kk < 4; ++kk) {
          const float4 xv = *(const float4*)&sX[gr * 16 + kk * 4];
          a0 += xv.x * wc0[4 * kk] + xv.y * wc0[4 * kk + 1] + xv.z * wc0[4 * kk + 2] + xv.w * wc0[4 * kk + 3];
          a1 += xv.x * wc1[4 * kk] + xv.y * wc1[4 * kk + 1] + xv.z * wc1[4 * kk + 2] + xv.w * wc1[4 * kk + 3];
        }
        hR[0][mt][i] = a0; hR[1][mt][i] = a1;
        sHb[gr * 264 + n0] = f2b(a0);
        sHb[gr * 264 + n1] = f2b(a1);
      }
  }
  __syncthreads();

  // ---- P2: QKV MFMA -> sQ f32 [32][200] (in sMb region) ----
  for (int pass = 0; pass < 2; ++pass) {
    const int nt = (pass == 0) ? wid : (wid < 4 ? 8 + wid : -1);
    if (nt < 0) break;
    f32x4 a0 = {0.f, 0.f, 0.f, 0.f}, a1 = {0.f, 0.f, 0.f, 0.f};
    #pragma unroll
    for (int ks = 0; ks < 8; ++ks) {
      const bf16x8 A0 = ldsFrag(sHb, nl * 264 + ks * 32 + rq * 8);
      const bf16x8 A1 = ldsFrag(sHb, (16 + nl) * 264 + ks * 32 + rq * 8);
      const bf16x8 Bf = ldw(wsf, FR_QKV + nt * 8 + ks, l);
      a0 = MFMA(A0, Bf, a0);
      a1 = MFMA(A1, Bf, a1);
    }
    const int n = nt * 16 + nl;
    const float bias = (n < 64) ? bq[n] : (n < 128) ? bk[n - 64] : bv[n - 128];
    const float scl = (n < 64) ? 0.25f : 1.0f;
    #pragma unroll
    for (int i = 0; i < 4; ++i) {
      sQ[(rq * 4 + i) * 200 + n] = (a0[i] + bias) * scl;
      sQ[(16 + rq * 4 + i) * 200 + n] = (a1[i] + bias) * scl;
    }
  }
  __syncthreads();

  // ---- P3: attention (fp32; 128 threads) -> sCb bf16 ----
  if (tid < 128) {
    const int bl = tid >> 5, hh = (tid >> 3) & 3, qi = tid & 7, rb = bl * 8;
    const float* qrow = &sQ[(rb + qi) * 200 + hh * 16];
    float qv[16];
    #pragma unroll
    for (int kk = 0; kk < 16; kk += 4) {
      const float4 q4 = *(const float4*)&qrow[kk];
      qv[kk] = q4.x; qv[kk + 1] = q4.y; qv[kk + 2] = q4.z; qv[kk + 3] = q4.w;
    }
    float lg[8];
    #pragma unroll
    for (int j = 0; j < 8; ++j) {
      const float* krow = &sQ[(rb + j) * 200 + 64 + hh * 16];
      float d = 0.f;
      #pragma unroll
      for (int kk = 0; kk < 16; kk += 4) {
        const float4 k4 = *(const float4*)&krow[kk];
        d += qv[kk] * k4.x + qv[kk + 1] * k4.y + qv[kk + 2] * k4.z + qv[kk + 3] * k4.w;
      }
      lg[j] = d;
    }
    float mx = lg[0];
    #pragma unroll
    for (int j = 1; j < 8; ++j) mx = fmaxf(mx, lg[j]);
    float ssum = 0.f;
    #pragma unroll
    for (int j = 0; j < 8; ++j) { lg[j] = __expf(lg[j] - mx); ssum += lg[j]; }
    const float inv = 1.0f / ssum;
    #pragma unroll
    for (int kk = 0; kk < 16; kk += 4) {
      float c0 = 0.f, c1 = 0.f, c2 = 0.f, c3 = 0.f;
      #pragma unroll
      for (int j = 0; j < 8; ++j) {
        const float4 v4 = *(const float4*)&sQ[(rb + j) * 200 + 128 + hh * 16 + kk];
        c0 += lg[j] * v4.x; c1 += lg[j] * v4.y; c2 += lg[j] * v4.z; c3 += lg[j] * v4.w;
      }
      const int cb = (rb + qi) * 72 + hh * 16 + kk;
      sCb[cb] = f2b(c0 * inv); sCb[cb + 1] = f2b(c1 * inv);
      sCb[cb + 2] = f2b(c2 * inv); sCb[cb + 3] = f2b(c3 * inv);
    }
  }
  __syncthreads();

  // ---- P4: WO MFMA + residual -> nv; LN1 -> hR(h1), sHb ----
  {
    #pragma unroll
    for (int j = 0; j < 2; ++j) {
      const int nt = wid * 2 + j;
      f32x4 a0 = {0.f, 0.f, 0.f, 0.f}, a1 = {0.f, 0.f, 0.f, 0.f};
      #pragma unroll
      for (int ks = 0; ks < 2; ++ks) {
        const bf16x8 A0 = ldsFrag(sCb, nl * 72 + ks * 32 + rq * 8);
        const bf16x8 A1 = ldsFrag(sCb, (16 + nl) * 72 + ks * 32 + rq * 8);
        const bf16x8 Bf = ldw(wsf, FR_WO + nt * 2 + ks, l);
        a0 = MFMA(A0, Bf, a0);
        a1 = MFMA(A1, Bf, a1);
      }
      const float bb = bo[j ? n1 : n0];
      #pragma unroll
      for (int i = 0; i < 4; ++i) {
        nv[j][0][i] = a0[i] + bb + hR[j][0][i];
        nv[j][1][i] = a1[i] + bb + hR[j][1][i];
      }
    }
  }
  ln_part(nv, sLN, wid, rq, nl);
  __syncthreads();
  {
    float mean[2][4], rstd[2][4];
    ln_stats(sLN, rq, mean, rstd);
    const float sc0 = ln1_s[n0], sc1 = ln1_s[n1], of0 = ln1_b[n0], of1 = ln1_b[n1];
    #pragma unroll
    for (int mt = 0; mt < 2; ++mt)
      #pragma unroll
      for (int i = 0; i < 4; ++i) {
        const int gr = mt * 16 + rq * 4 + i;
        const float o0 = sc0 * (nv[0][mt][i] - mean[mt][i]) * rstd[mt][i] + of0;
        const float o1 = sc1 * (nv[1][mt][i] - mean[mt][i]) * rstd[mt][i] + of1;
        hR[0][mt][i] = o0; hR[1][mt][i] = o1;
        sHb[gr * 264 + n0] = f2b(o0);
        sHb[gr * 264 + n1] = f2b(o1);
      }
  }
  __syncthreads();

  // ---- P5: gate = softmax(h1 @ wg + bg) from bf16 h1 (128 threads) ----
  if (tid < 128) {
    const int r = tid >> 2, e = tid & 3;
    float d = bg[e];
    #pragma unroll 4
    for (int k8 = 0; k8 < 32; ++k8) {
      const uint4 u = *(const uint4*)(sHb + r * 264 + k8 * 8);
      const float* wp = &wg[k8 * 32 + e];
      d += b2f(u.x & 0xffffu) * wp[0]  + b2f(u.x >> 16) * wp[4]
         + b2f(u.y & 0xffffu) * wp[8]  + b2f(u.y >> 16) * wp[12]
         + b2f(u.z & 0xffffu) * wp[16] + b2f(u.z >> 16) * wp[20]
         + b2f(u.w & 0xffffu) * wp[24] + b2f(u.w >> 16) * wp[28];
    }
    float mx = fmaxf(d, __shfl_xor(d, 1, 64));
    mx = fmaxf(mx, __shfl_xor(mx, 2, 64));
    const float p = __expf(d - mx);
    float ss = p + __shfl_xor(p, 1, 64);
    ss += __shfl_xor(ss, 2, 64);
    sG[r * 4 + e] = p / ss;
  }
  __syncthreads();

  // ---- P6: MoE1 MFMA: hid = gate * relu(h1@w1 + b1) -> sMb bf16 [32][520] ----
  {
    f32x4 acc[4][2];
    #pragma unroll
    for (int j = 0; j < 4; ++j)
      #pragma unroll
      for (int mt = 0; mt < 2; ++mt) acc[j][mt] = {0.f, 0.f, 0.f, 0.f};
    #pragma unroll
    for (int ks = 0; ks < 8; ++ks) {
      const bf16x8 A0 = ldsFrag(sHb, nl * 264 + ks * 32 + rq * 8);
      const bf16x8 A1 = ldsFrag(sHb, (16 + nl) * 264 + ks * 32 + rq * 8);
      #pragma unroll
      for (int j = 0; j < 4; ++j) {
        const bf16x8 Bf = ldw(wsf, FR_W1 + (wid * 4 + j) * 8 + ks, l);
        acc[j][0] = MFMA(A0, Bf, acc[j][0]);
        acc[j][1] = MFMA(A1, Bf, acc[j][1]);
      }
    }
    #pragma unroll
    for (int j = 0; j < 4; ++j) {
      const int n = (wid * 4 + j) * 16 + nl, e = n >> 7;
      const float b1v = b1[e * 128 + (n & 127)];
      #pragma unroll
      for (int mt = 0; mt < 2; ++mt)
        #pragma unroll
        for (int i = 0; i < 4; ++i) {
          const int gr = mt * 16 + rq * 4 + i;
          const float g = sG[gr * 4 + e];
          sMb[gr * 520 + n] = f2b(g * fmaxf(acc[j][mt][i] + b1v, 0.f));
        }
    }
  }
  __syncthreads();

  // ---- P7: MoE2 MFMA + gate-weighted b2 + residual -> nv; LN2 -> hR(h2), sHb ----
  {
    f32x4 acc[2][2];
    #pragma unroll
    for (int j = 0; j < 2; ++j)
      #pragma unroll
      for (int mt = 0; mt < 2; ++mt) acc[j][mt] = {0.f, 0.f, 0.f, 0.f};
    #pragma unroll
    for (int ks = 0; ks < 16; ++ks) {
      const bf16x8 A0 = ldsFrag(sMb, nl * 520 + ks * 32 + rq * 8);
      const bf16x8 A1 = ldsFrag(sMb, (16 + nl) * 520 + ks * 32 + rq * 8);
      #pragma unroll
      for (int j = 0; j < 2; ++j) {
        const bf16x8 Bf = ldw(wsf, FR_W2 + (wid * 2 + j) * 16 + ks, l);
        acc[j][0] = MFMA(A0, Bf, acc[j][0]);
        acc[j][1] = MFMA(A1, Bf, acc[j][1]);
      }
    }
    #pragma unroll
    for (int j = 0; j < 2; ++j) {
      const int n = j ? n1 : n0;
      const float bA = b2[n], bB = b2[256 + n], bC = b2[512 + n], bD = b2[768 + n];
      #pragma unroll
      for (int mt = 0; mt < 2; ++mt)
        #pragma unroll
        for (int i = 0; i < 4; ++i) {
          const int gr = mt * 16 + rq * 4 + i;
          nv[j][mt][i] = acc[j][mt][i] + sG[gr * 4 + 0] * bA + sG[gr * 4 + 1] * bB +
                         sG[gr * 4 + 2] * bC + sG[gr * 4 + 3] * bD + hR[j][mt][i];
        }
    }
  }
  ln_part(nv, sLN, wid, rq, nl);
  __syncthreads();
  {
    float mean[2][4], rstd[2][4];
    ln_stats(sLN, rq, mean, rstd);
    const float sc0 = ln2_s[n0], sc1 = ln2_s[n1], of0 = ln2_b[n0], of1 = ln2_b[n1];
    #pragma unroll
    for (int mt = 0; mt < 2; ++mt)
      #pragma unroll
      for (int i = 0; i < 4; ++i) {
        const int gr = mt * 16 + rq * 4 + i;
        const float o0 = sc0 * (nv[0][mt][i] - mean[mt][i]) * rstd[mt][i] + of0;
        const float o1 = sc1 * (nv[1][mt][i] - mean[mt][i]) * rstd[mt][i] + of1;
        hR[0][mt][i] = o0; hR[1][mt][i] = o1;
        sHb[gr * 264 + n0] = f2b(o0);
        sHb[gr * 264 + n1] = f2b(o1);
      }
  }
  __syncthreads();

  // ---- P8: conv = 5-tap block-sparse MFMA + padc + residual -> nv ----
  {
    const unsigned int ENC[5] = {0x4F320FFFu, 0x54F310FFu, 0x76543210u, 0xFF764F32u, 0xFFF754F3u};
    f32x4 acc[2][2];
    #pragma unroll
    for (int j = 0; j < 2; ++j) {
      const int n = j ? n1 : n0;
      #pragma unroll
      for (int mt = 0; mt < 2; ++mt)
        #pragma unroll
        for (int i = 0; i < 4; ++i)
          acc[j][mt][i] = padc[((rq * 4 + i) & 7) * 256 + n];
    }
    #pragma unroll
    for (int tap = 0; tap < 5; ++tap) {
      const int nib = (int)((ENC[tap] >> ((nl & 7) * 4)) & 0xF);
      const bool valid = (nib != 15);
      const int srow = (nl & 8) + (nib & 7);
      #pragma unroll
      for (int ks = 0; ks < 8; ++ks) {
        FragU fa0, fa1;
        fa0.u = *(const uint4*)(sHb + srow * 264 + ks * 32 + rq * 8);
        fa1.u = *(const uint4*)(sHb + (16 + srow) * 264 + ks * 32 + rq * 8);
        if (!valid) { fa0.u = make_uint4(0, 0, 0, 0); fa1.u = make_uint4(0, 0, 0, 0); }
        #pragma unroll
        for (int j = 0; j < 2; ++j) {
          const bf16x8 Bf = ldw(wsf, FR_CONV + tap * 128 + (wid * 2 + j) * 8 + ks, l);
          acc[j][0] = MFMA(fa0.h, Bf, acc[j][0]);
          acc[j][1] = MFMA(fa1.h, Bf, acc[j][1]);
        }
      }
    }
    #pragma unroll
    for (int j = 0; j < 2; ++j)
      #pragma unroll
      for (int mt = 0; mt < 2; ++mt)
        #pragma unroll
        for (int i = 0; i < 4; ++i)
          nv[j][mt][i] = acc[j][mt][i] + hR[j][mt][i];
  }
  ln_part(nv, sLN, wid, rq, nl);
  __syncthreads();

  // ---- LN3 -> global out ----
  {
    float mean[2][4], rstd[2][4];
    ln_stats(sLN, rq, mean, rstd);
    const float sc0 = ln3_s[n0], sc1 = ln3_s[n1], of0 = ln3_b[n0], of1 = ln3_b[n1];
    float* ob = out + (size_t)blockIdx.x * 32 * 256;
    #pragma unroll
    for (int mt = 0; mt < 2; ++mt)
      #pragma unroll
      for (int i = 0; i < 4; ++i) {
        const int gr = mt * 16 + rq * 4 + i;
        ob[gr * 256 + n0] = sc0 * (nv[0][mt][i] - mean[mt][i]) * rstd[mt][i] + of0;
        ob[gr * 256 + n1] = sc1 * (nv[1][mt][i] - mean[mt][i]) * rstd[mt][i] + of1;
      }
  }
}

// ---------------------------------------------------------------------------
extern "C" void kernel_launch(void* const* d_in, const int* in_sizes, int n_in,
                              void* d_out, int out_size, void* d_ws, size_t ws_size,
                              hipStream_t stream) {
  const float* x       = (const float*)d_in[0];
  const float* w_embed = (const float*)d_in[1];
  const float* b_embed = (const float*)d_in[2];
  const float* wq      = (const float*)d_in[3];
  const float* bq      = (const float*)d_in[4];
  const float* wk      = (const float*)d_in[5];
  const float* bk      = (const float*)d_in[6];
  const float* wv      = (const float*)d_in[7];
  const float* bv      = (const float*)d_in[8];
  const float* wo      = (const float*)d_in[9];
  const float* bo      = (const float*)d_in[10];
  const float* ln1_s   = (const float*)d_in[11];
  const float* ln1_b   = (const float*)d_in[12];
  const float* wg      = (const float*)d_in[13];
  const float* bg      = (const float*)d_in[14];
  const float* w1      = (const float*)d_in[15];
  const float* b1      = (const float*)d_in[16];
  const float* w2      = (const float*)d_in[17];
  const float* b2      = (const float*)d_in[18];
  const float* ln2_s   = (const float*)d_in[19];
  const float* ln2_b   = (const float*)d_in[20];
  const float* pad_vec = (const float*)d_in[21];
  const float* conv_w  = (const float*)d_in[22];
  const float* conv_b  = (const float*)d_in[23];
  const float* ln3_s   = (const float*)d_in[24];
  const float* ln3_b   = (const float*)d_in[25];

  unsigned short* wsb = (unsigned short*)d_ws;
  float* padc = (float*)((char*)d_ws + PADC_BYTE_OFF);

  prep_weights<<<320, 256, 0, stream>>>(wq, wk, wv, wo, w1, w2, conv_w, wsb);
  padc_kernel<<<8, 1024, 0, stream>>>(pad_vec, conv_w, conv_b, padc);
  fused_main<<<4096, 512, 0, stream>>>(
      x, w_embed, b_embed, bq, bk, bv, bo, ln1_s, ln1_b, wg, bg, b1, b2,
      ln2_s, ln2_b, ln3_s, ln3_b, (const uint4*)d_ws, padc, (float*)d_out);
}